// Round 2
// baseline (3055.926 us; speedup 1.0000x reference)
//
#include <hip/hip_runtime.h>

// ---------------------------------------------------------------------------
// RecurrentKDA on MI355X (gfx950)
// Pipeline: convert_w -> ln -> gemm<0> (q,k,v,a,beta) -> scan -> gemm<1> (+x)
// GEMMs: fp16 hi/lo split (3x mfma_f32_16x16x32_f16) for ~fp32 accuracy.
// Scan: column-parallel delta rule, 16 lanes/column, DPP reductions.
// ws budget ~214 MiB; k (fp32) aliased into d_out[0..64MiB) (dead by gemm<1>).
// ---------------------------------------------------------------------------

#define TSEQ 4096
#define DMODEL 1024
#define NHEADS 16
#define DK 64
#define BATCH 4
#define MROWS (BATCH * TSEQ)        // 16384
#define N1PAD 4224                  // q|k|v|g (4096) + beta(16) + pad, 33 tiles
#define NB_TOT 5248                 // N1PAD + 1024 (Wo)
#define WSCALE 1024.0f
#define INV_WSCALE (1.0f / 1024.0f)

typedef _Float16 f16x8 __attribute__((ext_vector_type(8)));
typedef _Float16 f16x4 __attribute__((ext_vector_type(4)));
typedef float f32x4 __attribute__((ext_vector_type(4)));

__device__ __forceinline__ float sigmoidf_(float x) {
    return 1.0f / (1.0f + __expf(-x));
}

// ---------------------------------------------------------------------------
// Weight convert: transpose + x1024 + fp16 hi/lo split.
// Dest Bt[n][k], n in [0,5248): 0..4095 Wq/Wk/Wv/Wg, 4096..4111 Wbeta,
// 4112..4223 zero pad, 4224..5247 Wo.  grid(32 ktiles, 164 ntiles), block(32,8)
// ---------------------------------------------------------------------------
__global__ __launch_bounds__(256) void convert_w(
    const float* __restrict__ Wq, const float* __restrict__ Wk,
    const float* __restrict__ Wv, const float* __restrict__ Wg,
    const float* __restrict__ Wbeta, const float* __restrict__ Wo,
    _Float16* __restrict__ Bth, _Float16* __restrict__ Btl)
{
    __shared__ float tile[32][33];
    const int k0 = blockIdx.x * 32;
    const int n0 = blockIdx.y * 32;
    const int tx = threadIdx.x, ty = threadIdx.y;
#pragma unroll
    for (int yy = 0; yy < 4; ++yy) {
        const int kk = k0 + ty + yy * 8;
        const int n  = n0 + tx;
        float val = 0.0f;
        if (n < 4096) {
            const float* W = (n < 1024) ? Wq : (n < 2048) ? Wk : (n < 3072) ? Wv : Wg;
            val = W[(size_t)kk * 1024 + (n & 1023)];
        } else if (n < 4112) {
            val = Wbeta[(size_t)kk * 16 + (n - 4096)];
        } else if (n >= 4224) {
            val = Wo[(size_t)kk * 1024 + (n - 4224)];
        }
        tile[tx][ty + yy * 8] = val * WSCALE;
    }
    __syncthreads();
#pragma unroll
    for (int yy = 0; yy < 4; ++yy) {
        const int nl = ty + yy * 8;
        const float v = tile[nl][tx];
        const _Float16 h = (_Float16)v;
        const size_t idx = (size_t)(n0 + nl) * 1024 + k0 + tx;
        Bth[idx] = h;
        Btl[idx] = (_Float16)(v - (float)h);
    }
}

// ---------------------------------------------------------------------------
// LayerNorm -> fp16 hi/lo A matrix [16384][1024].  One block per row.
// ---------------------------------------------------------------------------
__global__ __launch_bounds__(256) void ln_kernel(
    const float* __restrict__ x, const float* __restrict__ gamma,
    const float* __restrict__ betaln,
    _Float16* __restrict__ Ah, _Float16* __restrict__ Al)
{
    const int row = blockIdx.x;
    const int tid = threadIdx.x;
    const float4 xv = *(const float4*)(x + (size_t)row * 1024 + tid * 4);
    float s1 = xv.x + xv.y + xv.z + xv.w;
    float s2 = xv.x * xv.x + xv.y * xv.y + xv.z * xv.z + xv.w * xv.w;
#pragma unroll
    for (int off = 32; off; off >>= 1) {
        s1 += __shfl_xor(s1, off);
        s2 += __shfl_xor(s2, off);
    }
    __shared__ float w1[4], w2[4];
    const int wid = tid >> 6, lane = tid & 63;
    if (lane == 0) { w1[wid] = s1; w2[wid] = s2; }
    __syncthreads();
    s1 = w1[0] + w1[1] + w1[2] + w1[3];
    s2 = w2[0] + w2[1] + w2[2] + w2[3];
    const float mean = s1 * (1.0f / 1024.0f);
    const float var  = s2 * (1.0f / 1024.0f) - mean * mean;
    const float rstd = 1.0f / sqrtf(var + 1e-5f);
    const float4 g4 = *(const float4*)(gamma + tid * 4);
    const float4 b4 = *(const float4*)(betaln + tid * 4);
    float xn[4];
    xn[0] = (xv.x - mean) * rstd * g4.x + b4.x;
    xn[1] = (xv.y - mean) * rstd * g4.y + b4.y;
    xn[2] = (xv.z - mean) * rstd * g4.z + b4.z;
    xn[3] = (xv.w - mean) * rstd * g4.w + b4.w;
    f16x4 hi, lo;
#pragma unroll
    for (int j = 0; j < 4; ++j) {
        const _Float16 h = (_Float16)xn[j];
        hi[j] = h;
        lo[j] = (_Float16)(xn[j] - (float)h);
    }
    *(f16x4*)(Ah + (size_t)row * 1024 + tid * 4) = hi;
    *(f16x4*)(Al + (size_t)row * 1024 + tid * 4) = lo;
}

// ---------------------------------------------------------------------------
// Split-fp16 GEMM: C[M,N] = A[M,K] * Bt[N,K]^T, 128x128 tile, 4 waves, BK=32.
// 3 MFMAs per fragment pair (hh + hl + lh).  MODE 0: scatter to q/k/v/a/beta
// (sigmoid on g,beta; q,v -> f16, k,a -> fp32).  MODE 1: out = C + x.
// ---------------------------------------------------------------------------
template <int MODE>
__global__ __launch_bounds__(256, 2) void gemm_split(
    const _Float16* __restrict__ Ah, const _Float16* __restrict__ Al,
    const _Float16* __restrict__ Bh, const _Float16* __restrict__ Bl,
    _Float16* __restrict__ qo, float* __restrict__ ko2, _Float16* __restrict__ vo,
    float* __restrict__ ao, float* __restrict__ bo,
    const float* __restrict__ xres, float* __restrict__ outp)
{
    __shared__ _Float16 smem[4 * 128 * 40];   // Ah,Al,Bh,Bl tiles, stride 40
    const int tid = threadIdx.x;
    const int nwg = gridDim.x;
    const int lin = (blockIdx.x & 7) * (nwg >> 3) + (blockIdx.x >> 3);  // XCD swizzle
    const int nt = lin >> 7;       // m-fastest: 128 consecutive wgs share B tile
    const int mt = lin & 127;

    const _Float16* sAh = Ah + (size_t)mt * 128 * 1024;
    const _Float16* sAl = Al + (size_t)mt * 128 * 1024;
    const _Float16* sBh = Bh + (size_t)nt * 128 * 1024;
    const _Float16* sBl = Bl + (size_t)nt * 128 * 1024;

    const int c0r = tid >> 2, c0s = tid & 3;
    const size_t goff0 = (size_t)c0r * 1024 + c0s * 8;
    const size_t goff1 = goff0 + (size_t)64 * 1024;
    const int loff0 = c0r * 40 + c0s * 8;
    const int loff1 = loff0 + 64 * 40;

    f16x8 st[8];
    auto LOAD = [&](int kt) {
        const int kofs = kt * 32;
        st[0] = *(const f16x8*)(sAh + goff0 + kofs);
        st[1] = *(const f16x8*)(sAh + goff1 + kofs);
        st[2] = *(const f16x8*)(sAl + goff0 + kofs);
        st[3] = *(const f16x8*)(sAl + goff1 + kofs);
        st[4] = *(const f16x8*)(sBh + goff0 + kofs);
        st[5] = *(const f16x8*)(sBh + goff1 + kofs);
        st[6] = *(const f16x8*)(sBl + goff0 + kofs);
        st[7] = *(const f16x8*)(sBl + goff1 + kofs);
    };
    auto WRITE = [&]() {
        *(f16x8*)(smem + 0 * 5120 + loff0) = st[0];
        *(f16x8*)(smem + 0 * 5120 + loff1) = st[1];
        *(f16x8*)(smem + 1 * 5120 + loff0) = st[2];
        *(f16x8*)(smem + 1 * 5120 + loff1) = st[3];
        *(f16x8*)(smem + 2 * 5120 + loff0) = st[4];
        *(f16x8*)(smem + 2 * 5120 + loff1) = st[5];
        *(f16x8*)(smem + 3 * 5120 + loff0) = st[6];
        *(f16x8*)(smem + 3 * 5120 + loff1) = st[7];
    };

    const int lane = tid & 63;
    const int wm = (tid >> 7) & 1, wn = (tid >> 6) & 1;
    const int row16 = lane & 15;
    const int kseg = (lane >> 4) * 8;

    f32x4 acc[4][4] = {};
    LOAD(0);
#pragma unroll 1
    for (int kt = 0; kt < 32; ++kt) {
        WRITE();
        if (kt + 1 < 32) LOAD(kt + 1);
        __syncthreads();
        f16x8 bhf[4], blf[4];
#pragma unroll
        for (int fn = 0; fn < 4; ++fn) {
            const int nrow = wn * 64 + fn * 16 + row16;
            bhf[fn] = *(const f16x8*)(smem + 2 * 5120 + nrow * 40 + kseg);
            blf[fn] = *(const f16x8*)(smem + 3 * 5120 + nrow * 40 + kseg);
        }
#pragma unroll
        for (int fm = 0; fm < 4; ++fm) {
            const int mrow = wm * 64 + fm * 16 + row16;
            const f16x8 ahf = *(const f16x8*)(smem + 0 * 5120 + mrow * 40 + kseg);
            const f16x8 alf = *(const f16x8*)(smem + 1 * 5120 + mrow * 40 + kseg);
#pragma unroll
            for (int fn = 0; fn < 4; ++fn) {
                acc[fm][fn] = __builtin_amdgcn_mfma_f32_16x16x32_f16(ahf, bhf[fn], acc[fm][fn], 0, 0, 0);
                acc[fm][fn] = __builtin_amdgcn_mfma_f32_16x16x32_f16(ahf, blf[fn], acc[fm][fn], 0, 0, 0);
                acc[fm][fn] = __builtin_amdgcn_mfma_f32_16x16x32_f16(alf, bhf[fn], acc[fm][fn], 0, 0, 0);
            }
        }
        __syncthreads();
    }

    // epilogue: C/D layout col = lane&15 (N), row = (lane>>4)*4 + i (M)
    const int mbase = mt * 128 + wm * 64 + (lane >> 4) * 4;
#pragma unroll
    for (int fm = 0; fm < 4; ++fm) {
#pragma unroll
        for (int fn = 0; fn < 4; ++fn) {
            const int n_in = wn * 64 + fn * 16 + row16;
#pragma unroll
            for (int i = 0; i < 4; ++i) {
                const int m = mbase + fm * 16 + i;
                const float val = acc[fm][fn][i] * INV_WSCALE;
                if (MODE == 0) {
                    const int n = nt * 128 + n_in;
                    const int bb = m >> 12, tt = m & 4095;
                    if (n < 4096) {
                        const int which = n >> 10;
                        const int hh = (n >> 6) & 15;
                        const int dd = n & 63;
                        const size_t idx =
                            ((((size_t)bb * 16 + hh) * 4096) + tt) * 64 + dd;
                        if (which == 0) qo[idx] = (_Float16)val;
                        else if (which == 1) ko2[idx] = val;
                        else if (which == 2) vo[idx] = (_Float16)val;
                        else ao[idx] = sigmoidf_(val);
                    } else {
                        const int n2 = n - 4096;
                        if (n2 < 16)
                            bo[((size_t)bb * 16 + n2) * 4096 + tt] = sigmoidf_(val);
                    }
                } else {
                    const size_t idx = (size_t)m * 1024 + (nt * 128 + n_in);
                    outp[idx] = val + xres[idx];
                }
            }
        }
    }
}

// ---------------------------------------------------------------------------
// Delta-rule scan.  Column e of S(b,h) is independent:
//   S1[d] = S[d] + b*k[d]*v[e];  A1[d] = a[d]*S1[d];  w = sum_d k[d]*A1[d]
//   S[d]  = A1[d] - b*k[d]*w;    o[e] = sum_d q[d]*S[d]
// 16 lanes per column (4 rows each), reductions = 4 DPP adds within 16 lanes.
// ---------------------------------------------------------------------------
template <int CTRL>
__device__ __forceinline__ float dpp_add(float x) {
    const int y = __builtin_amdgcn_update_dpp(0, __float_as_int(x), CTRL, 0xF, 0xF, true);
    return x + __int_as_float(y);
}
__device__ __forceinline__ float reduce16(float x) {
    x = dpp_add<0xB1>(x);    // quad_perm [1,0,3,2]
    x = dpp_add<0x4E>(x);    // quad_perm [2,3,0,1]
    x = dpp_add<0x124>(x);   // row_ror:4
    x = dpp_add<0x128>(x);   // row_ror:8
    return x;
}

__global__ __launch_bounds__(256) void scan_kernel(
    const _Float16* __restrict__ qb, const float* __restrict__ kb,
    const _Float16* __restrict__ vb, const float* __restrict__ ab,
    const float* __restrict__ betab,
    _Float16* __restrict__ oh, _Float16* __restrict__ ol,
    float* __restrict__ sfinal)
{
    const int bid = blockIdx.x;
    const int bh = bid & 63;
    const int cbk = bid >> 6;        // 0..3
    const int tid = threadIdx.x;
    const int grp = tid >> 4;        // 0..15 -> column within block
    const int r16 = tid & 15;
    const int e = cbk * 16 + grp;
    const int r4 = r16 * 4;
    const int b = bh >> 4, h = bh & 15;

    const _Float16* qg = qb + (size_t)bh * TSEQ * 64 + r4;
    const float*    kg = kb + (size_t)bh * TSEQ * 64 + r4;
    const float*    ag = ab + (size_t)bh * TSEQ * 64 + r4;
    const _Float16* vg = vb + (size_t)bh * TSEQ * 64 + e;
    const float*    bg = betab + (size_t)bh * TSEQ;

    _Float16* ohp = oh + (size_t)b * TSEQ * 1024 + h * 64 + e;
    _Float16* olp = ol + (size_t)b * TSEQ * 1024 + h * 64 + e;

    float S0 = 0.f, S1 = 0.f, S2 = 0.f, S3 = 0.f;

    for (int t = 0; t < TSEQ; ++t) {
        const float4 k4 = *(const float4*)(kg + (size_t)t * 64);
        const float4 a4 = *(const float4*)(ag + (size_t)t * 64);
        const f16x4 q4h = *(const f16x4*)(qg + (size_t)t * 64);
        const float vE = (float)vg[(size_t)t * 64];
        const float bt = bg[t];

        const float bk0 = bt * k4.x, bk1 = bt * k4.y;
        const float bk2 = bt * k4.z, bk3 = bt * k4.w;
        const float A0 = a4.x * fmaf(bk0, vE, S0);
        const float A1 = a4.y * fmaf(bk1, vE, S1);
        const float A2 = a4.z * fmaf(bk2, vE, S2);
        const float A3 = a4.w * fmaf(bk3, vE, S3);
        float w = fmaf(k4.x, A0, fmaf(k4.y, A1, fmaf(k4.z, A2, k4.w * A3)));
        w = reduce16(w);
        S0 = fmaf(-bk0, w, A0);
        S1 = fmaf(-bk1, w, A1);
        S2 = fmaf(-bk2, w, A2);
        S3 = fmaf(-bk3, w, A3);
        float o = fmaf((float)q4h[0], S0, fmaf((float)q4h[1], S1,
                  fmaf((float)q4h[2], S2, (float)q4h[3] * S3)));
        o = reduce16(o);
        if (r16 == 0) {
            const _Float16 hh = (_Float16)o;
            ohp[(size_t)t * 1024] = hh;
            olp[(size_t)t * 1024] = (_Float16)(o - (float)hh);
        }
    }
    const size_t sbase = ((size_t)bh * 64 + r4) * 64 + e;
    sfinal[sbase]       = S0;
    sfinal[sbase + 64]  = S1;
    sfinal[sbase + 128] = S2;
    sfinal[sbase + 192] = S3;
}

// ---------------------------------------------------------------------------
extern "C" void kernel_launch(void* const* d_in, const int* in_sizes, int n_in,
                              void* d_out, int out_size, void* d_ws, size_t ws_size,
                              hipStream_t stream)
{
    const float* x      = (const float*)d_in[0];
    const float* Wq     = (const float*)d_in[1];
    const float* Wk     = (const float*)d_in[2];
    const float* Wv     = (const float*)d_in[3];
    const float* Wg     = (const float*)d_in[4];
    const float* Wbeta  = (const float*)d_in[5];
    const float* Wo     = (const float*)d_in[6];
    const float* gamma  = (const float*)d_in[7];
    const float* betaln = (const float*)d_in[8];
    float* out = (float*)d_out;

    char* ws = (char*)d_ws;
    size_t off = 0;
    auto alloc = [&](size_t bytes) {
        size_t r = off;
        off += (bytes + 1023) & ~(size_t)1023;
        return r;
    };
    _Float16* Ah  = (_Float16*)(ws + alloc((size_t)MROWS * 1024 * 2));
    _Float16* Al  = (_Float16*)(ws + alloc((size_t)MROWS * 1024 * 2));
    _Float16* Bth = (_Float16*)(ws + alloc((size_t)NB_TOT * 1024 * 2));
    _Float16* Btl = (_Float16*)(ws + alloc((size_t)NB_TOT * 1024 * 2));
    float*    ab  = (float*)   (ws + alloc((size_t)MROWS * 1024 * 4));
    _Float16* vh  = (_Float16*)(ws + alloc((size_t)MROWS * 1024 * 2));
    _Float16* qh  = (_Float16*)(ws + alloc((size_t)MROWS * 1024 * 2));
    float*    betab = (float*) (ws + alloc((size_t)64 * TSEQ * 4));
    // ws-size guard (diagnostic: if insufficient, fail with wrong values, not a fault)
    if (ws_size < off) return;
    // k (fp32) lives in d_out[0 .. 16M floats) — dead before gemm<1> overwrites.
    float* kb = out;
    // o (hi/lo fp16) aliases A (dead after gemm<0>)
    _Float16* Oh = Ah;
    _Float16* Ol = Al;

    convert_w<<<dim3(32, 164), dim3(32, 8), 0, stream>>>(Wq, Wk, Wv, Wg, Wbeta, Wo, Bth, Btl);
    ln_kernel<<<MROWS, 256, 0, stream>>>(x, gamma, betaln, Ah, Al);
    gemm_split<0><<<33 * 128, 256, 0, stream>>>(Ah, Al, Bth, Btl,
                                                qh, kb, vh, ab, betab,
                                                nullptr, nullptr);
    scan_kernel<<<256, 256, 0, stream>>>(qh, kb, vh, ab, betab, Oh, Ol,
                                         out + (size_t)MROWS * 1024);
    gemm_split<1><<<8 * 128, 256, 0, stream>>>(Oh, Ol,
                                               Bth + (size_t)N1PAD * 1024,
                                               Btl + (size_t)N1PAD * 1024,
                                               nullptr, nullptr, nullptr, nullptr, nullptr,
                                               x, out);
}

// Round 5
// 1581.547 us; speedup vs baseline: 1.9322x; 1.9322x over previous
//
#include <hip/hip_runtime.h>

// ---------------------------------------------------------------------------
// RecurrentKDA on MI355X (gfx950)
// Pipeline: convert_w -> ln -> gemm<0> (q,k,v,a,beta) -> scan -> gemm<1> (+x)
// GEMMs: fp16 hi/lo split (3x mfma_f32_16x16x32_f16) for ~fp32 accuracy.
// Scan: column-parallel delta rule, 16 lanes/column, DPP reductions,
//       8-step double-buffered register prefetch (R2: latency was exposed,
//       VALUBusy 11%, 1380 cy/step = one L2/HBM round trip per step).
// ws budget ~214 MiB; k (fp32) aliased into d_out[0..64MiB) (dead by gemm<1>).
// ---------------------------------------------------------------------------

#define TSEQ 4096
#define DMODEL 1024
#define NHEADS 16
#define DK 64
#define BATCH 4
#define MROWS (BATCH * TSEQ)        // 16384
#define N1PAD 4224                  // q|k|v|g (4096) + beta(16) + pad, 33 tiles
#define NB_TOT 5248                 // N1PAD + 1024 (Wo)
#define WSCALE 1024.0f
#define INV_WSCALE (1.0f / 1024.0f)

typedef _Float16 f16x8 __attribute__((ext_vector_type(8)));
typedef _Float16 f16x4 __attribute__((ext_vector_type(4)));
typedef float f32x4 __attribute__((ext_vector_type(4)));

__device__ __forceinline__ float sigmoidf_(float x) {
    return 1.0f / (1.0f + __expf(-x));
}

// ---------------------------------------------------------------------------
// Weight convert: transpose + x1024 + fp16 hi/lo split.
// ---------------------------------------------------------------------------
__global__ __launch_bounds__(256) void convert_w(
    const float* __restrict__ Wq, const float* __restrict__ Wk,
    const float* __restrict__ Wv, const float* __restrict__ Wg,
    const float* __restrict__ Wbeta, const float* __restrict__ Wo,
    _Float16* __restrict__ Bth, _Float16* __restrict__ Btl)
{
    __shared__ float tile[32][33];
    const int k0 = blockIdx.x * 32;
    const int n0 = blockIdx.y * 32;
    const int tx = threadIdx.x, ty = threadIdx.y;
#pragma unroll
    for (int yy = 0; yy < 4; ++yy) {
        const int kk = k0 + ty + yy * 8;
        const int n  = n0 + tx;
        float val = 0.0f;
        if (n < 4096) {
            const float* W = (n < 1024) ? Wq : (n < 2048) ? Wk : (n < 3072) ? Wv : Wg;
            val = W[(size_t)kk * 1024 + (n & 1023)];
        } else if (n < 4112) {
            val = Wbeta[(size_t)kk * 16 + (n - 4096)];
        } else if (n >= 4224) {
            val = Wo[(size_t)kk * 1024 + (n - 4224)];
        }
        tile[tx][ty + yy * 8] = val * WSCALE;
    }
    __syncthreads();
#pragma unroll
    for (int yy = 0; yy < 4; ++yy) {
        const int nl = ty + yy * 8;
        const float v = tile[nl][tx];
        const _Float16 h = (_Float16)v;
        const size_t idx = (size_t)(n0 + nl) * 1024 + k0 + tx;
        Bth[idx] = h;
        Btl[idx] = (_Float16)(v - (float)h);
    }
}

// ---------------------------------------------------------------------------
// LayerNorm -> fp16 hi/lo A matrix [16384][1024].  One block per row.
// ---------------------------------------------------------------------------
__global__ __launch_bounds__(256) void ln_kernel(
    const float* __restrict__ x, const float* __restrict__ gamma,
    const float* __restrict__ betaln,
    _Float16* __restrict__ Ah, _Float16* __restrict__ Al)
{
    const int row = blockIdx.x;
    const int tid = threadIdx.x;
    const float4 xv = *(const float4*)(x + (size_t)row * 1024 + tid * 4);
    float s1 = xv.x + xv.y + xv.z + xv.w;
    float s2 = xv.x * xv.x + xv.y * xv.y + xv.z * xv.z + xv.w * xv.w;
#pragma unroll
    for (int off = 32; off; off >>= 1) {
        s1 += __shfl_xor(s1, off);
        s2 += __shfl_xor(s2, off);
    }
    __shared__ float w1[4], w2[4];
    const int wid = tid >> 6, lane = tid & 63;
    if (lane == 0) { w1[wid] = s1; w2[wid] = s2; }
    __syncthreads();
    s1 = w1[0] + w1[1] + w1[2] + w1[3];
    s2 = w2[0] + w2[1] + w2[2] + w2[3];
    const float mean = s1 * (1.0f / 1024.0f);
    const float var  = s2 * (1.0f / 1024.0f) - mean * mean;
    const float rstd = 1.0f / sqrtf(var + 1e-5f);
    const float4 g4 = *(const float4*)(gamma + tid * 4);
    const float4 b4 = *(const float4*)(betaln + tid * 4);
    float xn[4];
    xn[0] = (xv.x - mean) * rstd * g4.x + b4.x;
    xn[1] = (xv.y - mean) * rstd * g4.y + b4.y;
    xn[2] = (xv.z - mean) * rstd * g4.z + b4.z;
    xn[3] = (xv.w - mean) * rstd * g4.w + b4.w;
    f16x4 hi, lo;
#pragma unroll
    for (int j = 0; j < 4; ++j) {
        const _Float16 h = (_Float16)xn[j];
        hi[j] = h;
        lo[j] = (_Float16)(xn[j] - (float)h);
    }
    *(f16x4*)(Ah + (size_t)row * 1024 + tid * 4) = hi;
    *(f16x4*)(Al + (size_t)row * 1024 + tid * 4) = lo;
}

// ---------------------------------------------------------------------------
// Split-fp16 GEMM: C[M,N] = A[M,K] * Bt[N,K]^T, 128x128 tile, 4 waves, BK=32.
// ---------------------------------------------------------------------------
template <int MODE>
__global__ __launch_bounds__(256, 2) void gemm_split(
    const _Float16* __restrict__ Ah, const _Float16* __restrict__ Al,
    const _Float16* __restrict__ Bh, const _Float16* __restrict__ Bl,
    _Float16* __restrict__ qo, float* __restrict__ ko2, _Float16* __restrict__ vo,
    float* __restrict__ ao, float* __restrict__ bo,
    const float* __restrict__ xres, float* __restrict__ outp)
{
    __shared__ _Float16 smem[4 * 128 * 40];   // Ah,Al,Bh,Bl tiles, stride 40
    const int tid = threadIdx.x;
    const int nwg = gridDim.x;
    const int lin = (blockIdx.x & 7) * (nwg >> 3) + (blockIdx.x >> 3);  // XCD swizzle
    const int nt = lin >> 7;       // m-fastest: 128 consecutive wgs share B tile
    const int mt = lin & 127;

    const _Float16* sAh = Ah + (size_t)mt * 128 * 1024;
    const _Float16* sAl = Al + (size_t)mt * 128 * 1024;
    const _Float16* sBh = Bh + (size_t)nt * 128 * 1024;
    const _Float16* sBl = Bl + (size_t)nt * 128 * 1024;

    const int c0r = tid >> 2, c0s = tid & 3;
    const size_t goff0 = (size_t)c0r * 1024 + c0s * 8;
    const size_t goff1 = goff0 + (size_t)64 * 1024;
    const int loff0 = c0r * 40 + c0s * 8;
    const int loff1 = loff0 + 64 * 40;

    f16x8 st[8];
    auto LOAD = [&](int kt) {
        const int kofs = kt * 32;
        st[0] = *(const f16x8*)(sAh + goff0 + kofs);
        st[1] = *(const f16x8*)(sAh + goff1 + kofs);
        st[2] = *(const f16x8*)(sAl + goff0 + kofs);
        st[3] = *(const f16x8*)(sAl + goff1 + kofs);
        st[4] = *(const f16x8*)(sBh + goff0 + kofs);
        st[5] = *(const f16x8*)(sBh + goff1 + kofs);
        st[6] = *(const f16x8*)(sBl + goff0 + kofs);
        st[7] = *(const f16x8*)(sBl + goff1 + kofs);
    };
    auto WRITE = [&]() {
        *(f16x8*)(smem + 0 * 5120 + loff0) = st[0];
        *(f16x8*)(smem + 0 * 5120 + loff1) = st[1];
        *(f16x8*)(smem + 1 * 5120 + loff0) = st[2];
        *(f16x8*)(smem + 1 * 5120 + loff1) = st[3];
        *(f16x8*)(smem + 2 * 5120 + loff0) = st[4];
        *(f16x8*)(smem + 2 * 5120 + loff1) = st[5];
        *(f16x8*)(smem + 3 * 5120 + loff0) = st[6];
        *(f16x8*)(smem + 3 * 5120 + loff1) = st[7];
    };

    const int lane = tid & 63;
    const int wm = (tid >> 7) & 1, wn = (tid >> 6) & 1;
    const int row16 = lane & 15;
    const int kseg = (lane >> 4) * 8;

    f32x4 acc[4][4] = {};
    LOAD(0);
#pragma unroll 1
    for (int kt = 0; kt < 32; ++kt) {
        WRITE();
        if (kt + 1 < 32) LOAD(kt + 1);
        __syncthreads();
        f16x8 bhf[4], blf[4];
#pragma unroll
        for (int fn = 0; fn < 4; ++fn) {
            const int nrow = wn * 64 + fn * 16 + row16;
            bhf[fn] = *(const f16x8*)(smem + 2 * 5120 + nrow * 40 + kseg);
            blf[fn] = *(const f16x8*)(smem + 3 * 5120 + nrow * 40 + kseg);
        }
#pragma unroll
        for (int fm = 0; fm < 4; ++fm) {
            const int mrow = wm * 64 + fm * 16 + row16;
            const f16x8 ahf = *(const f16x8*)(smem + 0 * 5120 + mrow * 40 + kseg);
            const f16x8 alf = *(const f16x8*)(smem + 1 * 5120 + mrow * 40 + kseg);
#pragma unroll
            for (int fn = 0; fn < 4; ++fn) {
                acc[fm][fn] = __builtin_amdgcn_mfma_f32_16x16x32_f16(ahf, bhf[fn], acc[fm][fn], 0, 0, 0);
                acc[fm][fn] = __builtin_amdgcn_mfma_f32_16x16x32_f16(ahf, blf[fn], acc[fm][fn], 0, 0, 0);
                acc[fm][fn] = __builtin_amdgcn_mfma_f32_16x16x32_f16(alf, bhf[fn], acc[fm][fn], 0, 0, 0);
            }
        }
        __syncthreads();
    }

    // epilogue: C/D layout col = lane&15 (N), row = (lane>>4)*4 + i (M)
    const int mbase = mt * 128 + wm * 64 + (lane >> 4) * 4;
#pragma unroll
    for (int fm = 0; fm < 4; ++fm) {
#pragma unroll
        for (int fn = 0; fn < 4; ++fn) {
            const int n_in = wn * 64 + fn * 16 + row16;
#pragma unroll
            for (int i = 0; i < 4; ++i) {
                const int m = mbase + fm * 16 + i;
                const float val = acc[fm][fn][i] * INV_WSCALE;
                if (MODE == 0) {
                    const int n = nt * 128 + n_in;
                    const int bb = m >> 12, tt = m & 4095;
                    if (n < 4096) {
                        const int which = n >> 10;
                        const int hh = (n >> 6) & 15;
                        const int dd = n & 63;
                        const size_t idx =
                            ((((size_t)bb * 16 + hh) * 4096) + tt) * 64 + dd;
                        if (which == 0) qo[idx] = (_Float16)val;
                        else if (which == 1) ko2[idx] = val;
                        else if (which == 2) vo[idx] = (_Float16)val;
                        else ao[idx] = sigmoidf_(val);
                    } else {
                        const int n2 = n - 4096;
                        if (n2 < 16)
                            bo[((size_t)bb * 16 + n2) * 4096 + tt] = sigmoidf_(val);
                    }
                } else {
                    const size_t idx = (size_t)m * 1024 + (nt * 128 + n_in);
                    outp[idx] = val + xres[idx];
                }
            }
        }
    }
}

// ---------------------------------------------------------------------------
// Delta-rule scan, latency-pipelined.
//   S1[d] = S[d] + b*k[d]*v[e];  A[d] = a[d]*S1[d];  w = sum_d k[d]*A[d]
//   S[d]  = A[d] - b*k[d]*w;     o[e] = q·A - w*(q·bk)   (avoids serial chain)
// 16 lanes per column (4 rows each); 3 interleaved DPP reduction chains;
// 8-step double-buffered register prefetch hides global-load latency.
// ---------------------------------------------------------------------------
template <int CTRL>
__device__ __forceinline__ float dpp_add(float x) {
    const int y = __builtin_amdgcn_update_dpp(0, __float_as_int(x), CTRL, 0xF, 0xF, true);
    return x + __int_as_float(y);
}

struct SBuf {
    f32x4 k[8];
    f32x4 a[8];
    f16x4 q[8];
    _Float16 v[8];
    float b[8];
};

__device__ __forceinline__ void load8(SBuf& s,
    const float* __restrict__ kg, const float* __restrict__ ag,
    const _Float16* __restrict__ qg, const _Float16* __restrict__ vg,
    const float* __restrict__ bg, int t0)
{
#pragma unroll
    for (int i = 0; i < 8; ++i) {
        const size_t o = (size_t)(t0 + i) * 64;
        s.k[i] = *(const f32x4*)(kg + o);
        s.a[i] = *(const f32x4*)(ag + o);
        s.q[i] = *(const f16x4*)(qg + o);
        s.v[i] = vg[o];
        s.b[i] = bg[t0 + i];
    }
}

__device__ __forceinline__ void step8(const SBuf& s,
    float& S0, float& S1, float& S2, float& S3,
    _Float16* __restrict__ ohp, _Float16* __restrict__ olp,
    int t0, bool w0)
{
#pragma unroll
    for (int i = 0; i < 8; ++i) {
        const float bt = s.b[i];
        const float vE = (float)s.v[i];
        const float k0 = s.k[i][0], k1 = s.k[i][1], k2 = s.k[i][2], k3 = s.k[i][3];
        const float bk0 = bt * k0, bk1 = bt * k1, bk2 = bt * k2, bk3 = bt * k3;
        const float A0 = s.a[i][0] * fmaf(bk0, vE, S0);
        const float A1 = s.a[i][1] * fmaf(bk1, vE, S1);
        const float A2 = s.a[i][2] * fmaf(bk2, vE, S2);
        const float A3 = s.a[i][3] * fmaf(bk3, vE, S3);
        const float q0 = (float)s.q[i][0], q1 = (float)s.q[i][1];
        const float q2 = (float)s.q[i][2], q3 = (float)s.q[i][3];
        float w  = fmaf(k0, A0, fmaf(k1, A1, fmaf(k2, A2, k3 * A3)));
        float ra = fmaf(q0, A0, fmaf(q1, A1, fmaf(q2, A2, q3 * A3)));
        float rb = fmaf(q0, bk0, fmaf(q1, bk1, fmaf(q2, bk2, q3 * bk3)));
        // three interleaved reduction chains (cover each other's DPP latency)
        w = dpp_add<0xB1>(w);  ra = dpp_add<0xB1>(ra);  rb = dpp_add<0xB1>(rb);
        w = dpp_add<0x4E>(w);  ra = dpp_add<0x4E>(ra);  rb = dpp_add<0x4E>(rb);
        w = dpp_add<0x124>(w); ra = dpp_add<0x124>(ra); rb = dpp_add<0x124>(rb);
        w = dpp_add<0x128>(w); ra = dpp_add<0x128>(ra); rb = dpp_add<0x128>(rb);
        S0 = fmaf(-bk0, w, A0);
        S1 = fmaf(-bk1, w, A1);
        S2 = fmaf(-bk2, w, A2);
        S3 = fmaf(-bk3, w, A3);
        const float o = fmaf(-rb, w, ra);
        if (w0) {
            const _Float16 hh = (_Float16)o;
            ohp[(size_t)(t0 + i) * 1024] = hh;
            olp[(size_t)(t0 + i) * 1024] = (_Float16)(o - (float)hh);
        }
    }
}

__global__ __launch_bounds__(256, 1) void scan_kernel(
    const _Float16* __restrict__ qb, const float* __restrict__ kb,
    const _Float16* __restrict__ vb, const float* __restrict__ ab,
    const float* __restrict__ betab,
    _Float16* __restrict__ oh, _Float16* __restrict__ ol,
    float* __restrict__ sfinal)
{
    const int bid = blockIdx.x;
    const int bh = bid & 63;
    const int cbk = bid >> 6;        // 0..3
    const int tid = threadIdx.x;
    const int grp = tid >> 4;        // 0..15 -> column within block
    const int r16 = tid & 15;
    const int e = cbk * 16 + grp;
    const int r4 = r16 * 4;
    const int b = bh >> 4, h = bh & 15;

    const _Float16* qg = qb + (size_t)bh * TSEQ * 64 + r4;
    const float*    kg = kb + (size_t)bh * TSEQ * 64 + r4;
    const float*    ag = ab + (size_t)bh * TSEQ * 64 + r4;
    const _Float16* vg = vb + (size_t)bh * TSEQ * 64 + e;
    const float*    bg = betab + (size_t)bh * TSEQ;

    _Float16* ohp = oh + (size_t)b * TSEQ * 1024 + h * 64 + e;
    _Float16* olp = ol + (size_t)b * TSEQ * 1024 + h * 64 + e;

    float S0 = 0.f, S1 = 0.f, S2 = 0.f, S3 = 0.f;
    const bool w0 = (r16 == 0);

    SBuf bufA, bufB;
    load8(bufA, kg, ag, qg, vg, bg, 0);
#pragma unroll 1
    for (int c = 0; c < TSEQ; c += 16) {
        load8(bufB, kg, ag, qg, vg, bg, c + 8);
        step8(bufA, S0, S1, S2, S3, ohp, olp, c, w0);
        if (c + 16 < TSEQ)
            load8(bufA, kg, ag, qg, vg, bg, c + 16);
        step8(bufB, S0, S1, S2, S3, ohp, olp, c + 8, w0);
    }

    const size_t sbase = ((size_t)bh * 64 + r4) * 64 + e;
    sfinal[sbase]       = S0;
    sfinal[sbase + 64]  = S1;
    sfinal[sbase + 128] = S2;
    sfinal[sbase + 192] = S3;
}

// ---------------------------------------------------------------------------
extern "C" void kernel_launch(void* const* d_in, const int* in_sizes, int n_in,
                              void* d_out, int out_size, void* d_ws, size_t ws_size,
                              hipStream_t stream)
{
    const float* x      = (const float*)d_in[0];
    const float* Wq     = (const float*)d_in[1];
    const float* Wk     = (const float*)d_in[2];
    const float* Wv     = (const float*)d_in[3];
    const float* Wg     = (const float*)d_in[4];
    const float* Wbeta  = (const float*)d_in[5];
    const float* Wo     = (const float*)d_in[6];
    const float* gamma  = (const float*)d_in[7];
    const float* betaln = (const float*)d_in[8];
    float* out = (float*)d_out;

    char* ws = (char*)d_ws;
    size_t off = 0;
    auto alloc = [&](size_t bytes) {
        size_t r = off;
        off += (bytes + 1023) & ~(size_t)1023;
        return r;
    };
    _Float16* Ah  = (_Float16*)(ws + alloc((size_t)MROWS * 1024 * 2));
    _Float16* Al  = (_Float16*)(ws + alloc((size_t)MROWS * 1024 * 2));
    _Float16* Bth = (_Float16*)(ws + alloc((size_t)NB_TOT * 1024 * 2));
    _Float16* Btl = (_Float16*)(ws + alloc((size_t)NB_TOT * 1024 * 2));
    float*    ab  = (float*)   (ws + alloc((size_t)MROWS * 1024 * 4));
    _Float16* vh  = (_Float16*)(ws + alloc((size_t)MROWS * 1024 * 2));
    _Float16* qh  = (_Float16*)(ws + alloc((size_t)MROWS * 1024 * 2));
    float*    betab = (float*) (ws + alloc((size_t)64 * TSEQ * 4));
    // ws-size guard (diagnostic: if insufficient, fail with wrong values, not a fault)
    if (ws_size < off) return;
    // k (fp32) lives in d_out[0 .. 16M floats) — dead before gemm<1> overwrites.
    float* kb = out;
    // o (hi/lo fp16) aliases A (dead after gemm<0>)
    _Float16* Oh = Ah;
    _Float16* Ol = Al;

    convert_w<<<dim3(32, 164), dim3(32, 8), 0, stream>>>(Wq, Wk, Wv, Wg, Wbeta, Wo, Bth, Btl);
    ln_kernel<<<MROWS, 256, 0, stream>>>(x, gamma, betaln, Ah, Al);
    gemm_split<0><<<33 * 128, 256, 0, stream>>>(Ah, Al, Bth, Btl,
                                                qh, kb, vh, ab, betab,
                                                nullptr, nullptr);
    scan_kernel<<<256, 256, 0, stream>>>(qh, kb, vh, ab, betab, Oh, Ol,
                                         out + (size_t)MROWS * 1024);
    gemm_split<1><<<8 * 128, 256, 0, stream>>>(Oh, Ol,
                                               Bth + (size_t)N1PAD * 1024,
                                               Btl + (size_t)N1PAD * 1024,
                                               nullptr, nullptr, nullptr, nullptr, nullptr,
                                               x, out);
}